// Round 1
// baseline (20702.605 us; speedup 1.0000x reference)
//
#include <hip/hip_runtime.h>
#include <math.h>

#define TSEQ 1024
#define NB   128
#define NIN  64
#define NH   256
#define NOUT 64
#define NWG  256
#define NTHR 512

// -------- input transpose: x[b][t][k] -> xT[t][k][b] --------
__global__ void xpose_kernel(const float* __restrict__ in, float* __restrict__ xT) {
  __shared__ float tile[64 * 129];
  const int t = blockIdx.x;
  {
    const int b  = threadIdx.x >> 1;          // 0..127
    const int k0 = (threadIdx.x & 1) * 32;    // 0 or 32
    const float* src = in + (size_t)b * (TSEQ * NIN) + (size_t)t * NIN + k0;
#pragma unroll 8
    for (int k = 0; k < 32; ++k) tile[(k0 + k) * 129 + b] = src[k];
  }
  __syncthreads();
  {
    const int k  = threadIdx.x >> 2;          // 0..63
    const int b0 = (threadIdx.x & 3) * 32;    // 0,32,64,96
    float* dst = xT + (size_t)t * (NIN * NB) + (size_t)k * NB + b0;
#pragma unroll 8
    for (int i = 0; i < 32; ++i) dst[i] = tile[k * 129 + b0 + i];
  }
}

// 8-FMA update: acc[g][bb] += w[g] * v[bb]
#define FMA8(w4, v2)                                        \
  acc00 += (w4).x * (v2).x; acc01 += (w4).x * (v2).y;       \
  acc10 += (w4).y * (v2).x; acc11 += (w4).y * (v2).y;       \
  acc20 += (w4).z * (v2).x; acc21 += (w4).z * (v2).y;       \
  acc30 += (w4).w * (v2).x; acc31 += (w4).w * (v2).y;

__device__ __forceinline__ float sigm(float v) { return 1.0f / (1.0f + expf(-v)); }

// -------- persistent 2-layer LSTM kernel --------
// wg w: a = w>>5 (b-tile, 16 rows), j = w&31 (col-tile, 8 h-cols)
// software pipeline per iteration it: L0(step it) || L1(step it-1) || OUT(step it-2)
// ONE grid barrier per iteration.
__global__ __launch_bounds__(NTHR, 1) void lstm_persist(
    const float* __restrict__ x,
    const float* __restrict__ Wih0, const float* __restrict__ Whh0,
    const float* __restrict__ bih0, const float* __restrict__ bhh0,
    const float* __restrict__ Wih1, const float* __restrict__ Whh1,
    const float* __restrict__ bih1, const float* __restrict__ bhh1,
    const float* __restrict__ Wlin, const float* __restrict__ blin,
    float* __restrict__ out,
    float* h0T, float* h1T, const float* xT, unsigned* bar, int use_xT)
{
  // LDS: weights gate-quad interleaved: Wt[k][c*4+g]
  __shared__ float Wt0[320 * 32];   // layer0: k 0..63 = x-part, 64..319 = h-part
  __shared__ float Wt1[512 * 32];   // layer1: k 0..255 = h0-part, 256..511 = h1-part
  __shared__ float Wlin2[2 * 256];  // 2 output rows for this wg
  __shared__ float red[4112];       // cross-wave partial sums (stride 514 per col)
  __shared__ float bias0[32], bias1[32], blinS[2];
  __shared__ float c0l[128], c1l[128];  // cell state [c][b] = c*16+b (wg-private)

  const int tid  = threadIdx.x;
  const int w    = blockIdx.x;
  const int a    = w >> 5;        // b-tile
  const int j    = w & 31;        // col-tile
  const int b0   = a * 16;
  const int jh0  = j * 8;
  const int lane = tid & 63;
  const int kw   = tid >> 6;      // wave id = k-split index (0..7)
  const int cl   = lane >> 3;     // col within tile (0..7)
  const int bp   = lane & 7;      // b-pair (0..7)

  // ---- one-time: load weights into LDS ----
  for (int idx = tid; idx < 32 * 320; idx += NTHR) {
    int row = idx / 320;          // c*4+g
    int k   = idx % 320;
    int c = row >> 2, g = row & 3;
    int grow = g * 256 + jh0 + c;
    float v = (k < 64) ? Wih0[grow * 64 + k] : Whh0[grow * 256 + (k - 64)];
    Wt0[k * 32 + row] = v;
  }
  for (int idx = tid; idx < 32 * 512; idx += NTHR) {
    int row = idx >> 9;
    int k   = idx & 511;
    int c = row >> 2, g = row & 3;
    int grow = g * 256 + jh0 + c;
    float v = (k < 256) ? Wih1[grow * 256 + k] : Whh1[grow * 256 + (k - 256)];
    Wt1[k * 32 + row] = v;
  }
  if (tid < 512) {
    int o2 = tid >> 8, k = tid & 255;
    Wlin2[tid] = Wlin[(2 * j + o2) * 256 + k];
  }
  if (tid < 32) {
    int c = tid >> 2, g = tid & 3;
    int grow = g * 256 + jh0 + c;
    bias0[tid] = bih0[grow] + bhh0[grow];
    bias1[tid] = bih1[grow] + bhh1[grow];
  }
  if (tid < 2) blinS[tid] = blin[2 * j + tid];
  if (tid < 128) { c0l[tid] = 0.0f; c1l[tid] = 0.0f; }
  __syncthreads();

  const int hstride = NH * NB;  // 32768 floats per buffer

  for (int it = 0; it <= TSEQ + 1; ++it) {
    const float* h0r = h0T + ((it + 1) & 1) * hstride;  // h0[it-1]
    float*       h0w = h0T + (it & 1) * hstride;        // h0[it]
    const float* h1r = h1T + (it & 1) * hstride;        // h1[it-2]
    float*       h1w = h1T + ((it + 1) & 1) * hstride;  // h1[it-1]

    // ================= L0: step = it =================
    if (it < TSEQ) {
      float acc00 = 0, acc01 = 0, acc10 = 0, acc11 = 0;
      float acc20 = 0, acc21 = 0, acc30 = 0, acc31 = 0;
      // x part: k in [8*kw, 8*kw+8)
      if (use_xT) {
        const float* xrow = xT + (size_t)it * (NIN * NB) + b0 + 2 * bp;
#pragma unroll
        for (int kk = 0; kk < 8; ++kk) {
          int k = 8 * kw + kk;
          float4 w4 = *(const float4*)&Wt0[k * 32 + cl * 4];
          float2 xv = *(const float2*)&xrow[k * NB];
          FMA8(w4, xv);
        }
      } else {
        const float* xb1 = x + (size_t)(b0 + 2 * bp) * (TSEQ * NIN) + (size_t)it * NIN;
        const float* xb2 = xb1 + (size_t)(TSEQ * NIN);
#pragma unroll
        for (int kk = 0; kk < 8; ++kk) {
          int k = 8 * kw + kk;
          float4 w4 = *(const float4*)&Wt0[k * 32 + cl * 4];
          float2 xv = make_float2(xb1[k], xb2[k]);
          FMA8(w4, xv);
        }
      }
      // h part: k in [32*kw, 32*kw+32)
      {
        const float* hq = h0r + b0 + 2 * bp;
#pragma unroll 8
        for (int kk = 0; kk < 32; ++kk) {
          int k = 32 * kw + kk;
          float4 w4 = *(const float4*)&Wt0[(64 + k) * 32 + cl * 4];
          float2 hv = *(const float2*)&hq[k * NB];
          FMA8(w4, hv);
        }
      }
      const int br = cl * 514 + kw * 16 + 2 * bp;
      *(float2*)&red[br + 0 * 128] = make_float2(acc00, acc01);
      *(float2*)&red[br + 1 * 128] = make_float2(acc10, acc11);
      *(float2*)&red[br + 2 * 128] = make_float2(acc20, acc21);
      *(float2*)&red[br + 3 * 128] = make_float2(acc30, acc31);
    }
    __syncthreads();
    if (it < TSEQ && tid < 128) {
      int c = tid >> 4, b = tid & 15;
      int base = c * 514 + b;
      float s0 = 0, s1 = 0, s2 = 0, s3 = 0;
#pragma unroll
      for (int q = 0; q < 8; ++q) {
        s0 += red[base + 0 * 128 + q * 16];
        s1 += red[base + 1 * 128 + q * 16];
        s2 += red[base + 2 * 128 + q * 16];
        s3 += red[base + 3 * 128 + q * 16];
      }
      s0 += bias0[c * 4 + 0];
      s1 += bias0[c * 4 + 1];
      s2 += bias0[c * 4 + 2];
      s3 += bias0[c * 4 + 3];
      float ig = sigm(s0), fg = sigm(s1), gg = tanhf(s2), og = sigm(s3);
      float cn = fg * c0l[tid] + ig * gg;
      c0l[tid] = cn;
      h0w[(jh0 + c) * NB + b0 + b] = og * tanhf(cn);
    }
    __syncthreads();

    // ================= L1: step = it-1 =================
    if (it >= 1 && it <= TSEQ) {
      float acc00 = 0, acc01 = 0, acc10 = 0, acc11 = 0;
      float acc20 = 0, acc21 = 0, acc30 = 0, acc31 = 0;
      {
        const float* hq = h0r + b0 + 2 * bp;   // h0[it-1]
#pragma unroll 8
        for (int kk = 0; kk < 32; ++kk) {
          int k = 32 * kw + kk;
          float4 w4 = *(const float4*)&Wt1[k * 32 + cl * 4];
          float2 hv = *(const float2*)&hq[k * NB];
          FMA8(w4, hv);
        }
      }
      {
        const float* hq = h1r + b0 + 2 * bp;   // h1[it-2]
#pragma unroll 8
        for (int kk = 0; kk < 32; ++kk) {
          int k = 32 * kw + kk;
          float4 w4 = *(const float4*)&Wt1[(256 + k) * 32 + cl * 4];
          float2 hv = *(const float2*)&hq[k * NB];
          FMA8(w4, hv);
        }
      }
      const int br = cl * 514 + kw * 16 + 2 * bp;
      *(float2*)&red[br + 0 * 128] = make_float2(acc00, acc01);
      *(float2*)&red[br + 1 * 128] = make_float2(acc10, acc11);
      *(float2*)&red[br + 2 * 128] = make_float2(acc20, acc21);
      *(float2*)&red[br + 3 * 128] = make_float2(acc30, acc31);
    }
    __syncthreads();
    if (it >= 1 && it <= TSEQ && tid < 128) {
      int c = tid >> 4, b = tid & 15;
      int base = c * 514 + b;
      float s0 = 0, s1 = 0, s2 = 0, s3 = 0;
#pragma unroll
      for (int q = 0; q < 8; ++q) {
        s0 += red[base + 0 * 128 + q * 16];
        s1 += red[base + 1 * 128 + q * 16];
        s2 += red[base + 2 * 128 + q * 16];
        s3 += red[base + 3 * 128 + q * 16];
      }
      s0 += bias1[c * 4 + 0];
      s1 += bias1[c * 4 + 1];
      s2 += bias1[c * 4 + 2];
      s3 += bias1[c * 4 + 3];
      float ig = sigm(s0), fg = sigm(s1), gg = tanhf(s2), og = sigm(s3);
      float cn = fg * c1l[tid] + ig * gg;
      c1l[tid] = cn;
      h1w[(jh0 + c) * NB + b0 + b] = og * tanhf(cn);
    }
    __syncthreads();

    // ================= OUT: step = it-2 =================
    if (it >= 2 && tid < 256) {
      int o2 = tid & 1, b = (tid >> 1) & 15, ks = tid >> 5;
      float acc = 0;
      const float* hq = h1r + b0 + b;   // h1[it-2]
#pragma unroll 8
      for (int k = 32 * ks; k < 32 * ks + 32; ++k)
        acc += Wlin2[o2 * 256 + k] * hq[k * NB];
      red[(o2 * 16 + b) * 8 + ks] = acc;
    }
    __syncthreads();
    if (it >= 2 && tid < 32) {
      int o2 = tid & 1, b = tid >> 1;
      float s = 0;
#pragma unroll
      for (int q = 0; q < 8; ++q) s += red[(o2 * 16 + b) * 8 + q];
      s += blinS[o2];
      out[(size_t)(b0 + b) * (TSEQ * NOUT) + (size_t)(it - 2) * NOUT + (2 * j + o2)] = s;
    }

    // ================= grid barrier =================
    __syncthreads();
    if (it <= TSEQ) {
      if (tid == 0) {
        __hip_atomic_fetch_add(bar, 1u, __ATOMIC_RELEASE, __HIP_MEMORY_SCOPE_AGENT);
        unsigned tgt = (unsigned)NWG * (unsigned)(it + 1);
        while (__hip_atomic_load(bar, __ATOMIC_RELAXED, __HIP_MEMORY_SCOPE_AGENT) < tgt)
          __builtin_amdgcn_s_sleep(2);
        __builtin_amdgcn_fence(__ATOMIC_ACQUIRE, "agent");
      }
      __syncthreads();
    }
  }
}

extern "C" void kernel_launch(void* const* d_in, const int* in_sizes, int n_in,
                              void* d_out, int out_size, void* d_ws, size_t ws_size,
                              hipStream_t stream) {
  const float* x    = (const float*)d_in[0];
  const float* Wih0 = (const float*)d_in[1];
  const float* Whh0 = (const float*)d_in[2];
  const float* bih0 = (const float*)d_in[3];
  const float* bhh0 = (const float*)d_in[4];
  const float* Wih1 = (const float*)d_in[5];
  const float* Whh1 = (const float*)d_in[6];
  const float* bih1 = (const float*)d_in[7];
  const float* bhh1 = (const float*)d_in[8];
  const float* Wlin = (const float*)d_in[9];
  const float* blin = (const float*)d_in[10];
  float* out = (float*)d_out;

  char* ws = (char*)d_ws;
  unsigned* bar = (unsigned*)ws;                         // [0, 1KB)
  float* h0T = (float*)(ws + 1024);                      // 2*32768 floats
  float* h1T = (float*)(ws + 1024 + 262144);             // 2*32768 floats
  float* xT  = (float*)(ws + (1 << 20));                 // 32 MB

  const size_t need_xT = (size_t)(1 << 20) + (size_t)TSEQ * NIN * NB * sizeof(float);
  const int use_xT = (ws_size >= need_xT) ? 1 : 0;

  // zero barrier counter + h state (covers [0, 1MB))
  size_t zbytes = (ws_size < (size_t)(1 << 20)) ? ws_size : (size_t)(1 << 20);
  hipMemsetAsync(d_ws, 0, zbytes, stream);

  if (use_xT) xpose_kernel<<<TSEQ, 256, 0, stream>>>(x, xT);

  lstm_persist<<<NWG, NTHR, 0, stream>>>(
      x, Wih0, Whh0, bih0, bhh0, Wih1, Whh1, bih1, bhh1, Wlin, blin,
      out, h0T, h1T, xT, bar, use_xT);
}

// Round 2
// 13647.417 us; speedup vs baseline: 1.5170x; 1.5170x over previous
//
#include <hip/hip_runtime.h>
#include <math.h>

#define TSEQ 1024
#define NB   128
#define NIN  64
#define NH   256
#define NOUT 64
#define NWG  256
#define NTHR 512
#define HS   (NH * NB)   // 32768 floats per h buffer

// -------- input transpose: x[b][t][k] -> xT[t][k][b] --------
__global__ void xpose_kernel(const float* __restrict__ in, float* __restrict__ xT) {
  __shared__ float tile[64 * 129];
  const int t = blockIdx.x;
  {
    const int b  = threadIdx.x >> 1;          // 0..127
    const int k0 = (threadIdx.x & 1) * 32;    // 0 or 32
    const float* src = in + (size_t)b * (TSEQ * NIN) + (size_t)t * NIN + k0;
#pragma unroll 8
    for (int k = 0; k < 32; ++k) tile[(k0 + k) * 129 + b] = src[k];
  }
  __syncthreads();
  {
    const int k  = threadIdx.x >> 2;          // 0..63
    const int b0 = (threadIdx.x & 3) * 32;    // 0,32,64,96
    float* dst = xT + (size_t)t * (NIN * NB) + (size_t)k * NB + b0;
#pragma unroll 8
    for (int i = 0; i < 32; ++i) dst[i] = tile[k * 129 + b0 + i];
  }
}

// 8-FMA update: acc[g][bb] += w[g] * v[bb]
#define FMA8(w4, v2)                                        \
  acc00 += (w4).x * (v2).x; acc01 += (w4).x * (v2).y;       \
  acc10 += (w4).y * (v2).x; acc11 += (w4).y * (v2).y;       \
  acc20 += (w4).z * (v2).x; acc21 += (w4).z * (v2).y;       \
  acc30 += (w4).w * (v2).x; acc31 += (w4).w * (v2).y;

__device__ __forceinline__ float sigm(float v) { return 1.0f / (1.0f + expf(-v)); }

// -------- persistent 2-layer LSTM kernel --------
// wg: a = bid&7 (batch group, 16 rows, likely XCD-local), j = bid>>3 (col-tile, 8 h-cols)
// pipeline per iteration it: L0(it) , L1(it-1) , OUT(it-2); per-GROUP flag barrier (no RMW).
// h0 double-buffered, h1 TRIPLE-buffered so the flag releases right after activations
// and OUT-final + flag propagation overlap the next poll.
__global__ __launch_bounds__(NTHR, 1) void lstm_persist(
    const float* __restrict__ x,
    const float* __restrict__ Wih0, const float* __restrict__ Whh0,
    const float* __restrict__ bih0, const float* __restrict__ bhh0,
    const float* __restrict__ Wih1, const float* __restrict__ Whh1,
    const float* __restrict__ bih1, const float* __restrict__ bhh1,
    const float* __restrict__ Wlin, const float* __restrict__ blin,
    float* __restrict__ out,
    float* __restrict__ h0T, float* __restrict__ h1T,
    const float* __restrict__ xT, unsigned* __restrict__ flags, int use_xT)
{
  // LDS: weights gate-quad interleaved: Wt[k][c*4+g]
  __shared__ float Wt0[320 * 32];   // layer0: k 0..63 = x-part, 64..319 = h-part (40KB)
  __shared__ float Wt1[512 * 32];   // layer1: k 0..255 = h0-part, 256..511 = h1-part (64KB)
  __shared__ float Wlin2[2 * 256];  // 2 output rows for this wg
  __shared__ float red0[32 * 130];  // L0 partials [r=c*4+g][ks*16+b], rowstride 130
  __shared__ float red1[32 * 130];  // L1 partials
  __shared__ float redO[288];       // OUT partials [(o2*16+b)*9 + ks]
  __shared__ float bias0[32], bias1[32], blinS[2];
  __shared__ float c0l[128], c1l[128];  // cell state [c*16+b] (wg-private)

  const int tid  = threadIdx.x;
  const int a    = blockIdx.x & 7;    // batch group (XCD-local if round-robin dispatch)
  const int j    = blockIdx.x >> 3;   // col-tile 0..31
  const int b0   = a * 16;
  const int jh0  = j * 8;
  const int lane = tid & 63;
  const int kw   = tid >> 6;      // wave id = k-split index (0..7)
  const int cl   = lane >> 3;     // col within tile (0..7)
  const int bp   = lane & 7;      // b-pair (0..7)

  // ---- one-time: load weights into LDS ----
  for (int idx = tid; idx < 32 * 320; idx += NTHR) {
    int row = idx / 320;          // c*4+g
    int k   = idx % 320;
    int c = row >> 2, g = row & 3;
    int grow = g * 256 + jh0 + c;
    float v = (k < 64) ? Wih0[grow * 64 + k] : Whh0[grow * 256 + (k - 64)];
    Wt0[k * 32 + row] = v;
  }
  for (int idx = tid; idx < 32 * 512; idx += NTHR) {
    int row = idx >> 9;
    int k   = idx & 511;
    int c = row >> 2, g = row & 3;
    int grow = g * 256 + jh0 + c;
    float v = (k < 256) ? Wih1[grow * 256 + k] : Whh1[grow * 256 + (k - 256)];
    Wt1[k * 32 + row] = v;
  }
  if (tid < 512) {
    int o2 = tid >> 8, k = tid & 255;
    Wlin2[tid] = Wlin[(2 * j + o2) * 256 + k];
  }
  if (tid < 32) {
    int c = tid >> 2, g = tid & 3;
    int grow = g * 256 + jh0 + c;
    bias0[tid] = bih0[grow] + bhh0[grow];
    bias1[tid] = bih1[grow] + bhh1[grow];
  }
  if (tid < 2) blinS[tid] = blin[2 * j + tid];
  if (tid < 128) { c0l[tid] = 0.0f; c1l[tid] = 0.0f; }
  __syncthreads();

  const int myflag = (a * 32 + j) * 16;   // 64B-spaced flag slot

  for (int it = 0; it <= TSEQ + 1; ++it) {
    // ---- poll: all 32 group flags >= it (means group finished acts of it-1) ----
    if (it >= 1 && tid < 64) {
      const unsigned tgt = (unsigned)it;
      const int fi = (a * 32 + (tid & 31)) * 16;
      while (true) {
        unsigned v = __hip_atomic_load(&flags[fi], __ATOMIC_RELAXED, __HIP_MEMORY_SCOPE_AGENT);
        if (__ballot(v >= tgt) == ~0ull) break;
        __builtin_amdgcn_s_sleep(1);
      }
      __builtin_amdgcn_fence(__ATOMIC_ACQUIRE, "agent");
    }
    __syncthreads();   // S1

    const float* h0r = h0T + ((it + 1) & 1) * HS;   // h0[it-1]
    float*       h0w = h0T + (it & 1) * HS;         // h0[it]
    const float* h1r = h1T + ((it + 1) % 3) * HS;   // h1[it-2]
    float*       h1w = h1T + ((it + 2) % 3) * HS;   // h1[it-1]

    // ================= A: L0 gates, step = it =================
    if (it < TSEQ) {
      float acc00 = 0, acc01 = 0, acc10 = 0, acc11 = 0;
      float acc20 = 0, acc21 = 0, acc30 = 0, acc31 = 0;
      if (use_xT) {
        const float* xrow = xT + (size_t)it * (NIN * NB) + b0 + 2 * bp;
#pragma unroll
        for (int kk = 0; kk < 8; ++kk) {
          int k = 8 * kw + kk;
          float4 w4 = *(const float4*)&Wt0[k * 32 + cl * 4];
          float2 xv = *(const float2*)&xrow[k * NB];
          FMA8(w4, xv);
        }
      } else {
        const float* xb1 = x + (size_t)(b0 + 2 * bp) * (TSEQ * NIN) + (size_t)it * NIN;
        const float* xb2 = xb1 + (size_t)(TSEQ * NIN);
#pragma unroll
        for (int kk = 0; kk < 8; ++kk) {
          int k = 8 * kw + kk;
          float4 w4 = *(const float4*)&Wt0[k * 32 + cl * 4];
          float2 xv = make_float2(xb1[k], xb2[k]);
          FMA8(w4, xv);
        }
      }
      {
        const float* hq = h0r + b0 + 2 * bp;
#pragma unroll 8
        for (int kk = 0; kk < 32; ++kk) {
          int k = 32 * kw + kk;
          float4 w4 = *(const float4*)&Wt0[(64 + k) * 32 + cl * 4];
          float2 hv = *(const float2*)&hq[k * NB];
          FMA8(w4, hv);
        }
      }
      const int base = cl * 520 + kw * 16 + 2 * bp;
      *(float2*)&red0[base +   0] = make_float2(acc00, acc01);
      *(float2*)&red0[base + 130] = make_float2(acc10, acc11);
      *(float2*)&red0[base + 260] = make_float2(acc20, acc21);
      *(float2*)&red0[base + 390] = make_float2(acc30, acc31);
    }

    // ================= B: L1 gates, step = it-1 =================
    if (it >= 1 && it <= TSEQ) {
      float acc00 = 0, acc01 = 0, acc10 = 0, acc11 = 0;
      float acc20 = 0, acc21 = 0, acc30 = 0, acc31 = 0;
      {
        const float* hq = h0r + b0 + 2 * bp;   // h0[it-1]
#pragma unroll 8
        for (int kk = 0; kk < 32; ++kk) {
          int k = 32 * kw + kk;
          float4 w4 = *(const float4*)&Wt1[k * 32 + cl * 4];
          float2 hv = *(const float2*)&hq[k * NB];
          FMA8(w4, hv);
        }
      }
      {
        const float* hq = h1r + b0 + 2 * bp;   // h1[it-2]
#pragma unroll 8
        for (int kk = 0; kk < 32; ++kk) {
          int k = 32 * kw + kk;
          float4 w4 = *(const float4*)&Wt1[(256 + k) * 32 + cl * 4];
          float2 hv = *(const float2*)&hq[k * NB];
          FMA8(w4, hv);
        }
      }
      const int base = cl * 520 + kw * 16 + 2 * bp;
      *(float2*)&red1[base +   0] = make_float2(acc00, acc01);
      *(float2*)&red1[base + 130] = make_float2(acc10, acc11);
      *(float2*)&red1[base + 260] = make_float2(acc20, acc21);
      *(float2*)&red1[base + 390] = make_float2(acc30, acc31);
    }
    __syncthreads();   // S2

    // ================= C: act0 (waves 0-1) || act1 (waves 2-3) || OUT-partial (waves 4-7)
    if (tid < 128) {
      if (it < TSEQ) {
        int c = tid >> 4, b = tid & 15;
        int base = (c * 4) * 130 + b;
        float s0 = 0, s1 = 0, s2 = 0, s3 = 0;
#pragma unroll
        for (int q = 0; q < 8; ++q) {
          s0 += red0[base + 0 * 130 + q * 16];
          s1 += red0[base + 1 * 130 + q * 16];
          s2 += red0[base + 2 * 130 + q * 16];
          s3 += red0[base + 3 * 130 + q * 16];
        }
        s0 += bias0[c * 4 + 0]; s1 += bias0[c * 4 + 1];
        s2 += bias0[c * 4 + 2]; s3 += bias0[c * 4 + 3];
        float ig = sigm(s0), fg = sigm(s1), gg = tanhf(s2), og = sigm(s3);
        float cn = fg * c0l[tid] + ig * gg;
        c0l[tid] = cn;
        h0w[(jh0 + c) * NB + b0 + b] = og * tanhf(cn);
      }
    } else if (tid < 256) {
      if (it >= 1 && it <= TSEQ) {
        int idx = tid - 128;
        int c = idx >> 4, b = idx & 15;
        int base = (c * 4) * 130 + b;
        float s0 = 0, s1 = 0, s2 = 0, s3 = 0;
#pragma unroll
        for (int q = 0; q < 8; ++q) {
          s0 += red1[base + 0 * 130 + q * 16];
          s1 += red1[base + 1 * 130 + q * 16];
          s2 += red1[base + 2 * 130 + q * 16];
          s3 += red1[base + 3 * 130 + q * 16];
        }
        s0 += bias1[c * 4 + 0]; s1 += bias1[c * 4 + 1];
        s2 += bias1[c * 4 + 2]; s3 += bias1[c * 4 + 3];
        float ig = sigm(s0), fg = sigm(s1), gg = tanhf(s2), og = sigm(s3);
        float cn = fg * c1l[idx] + ig * gg;
        c1l[idx] = cn;
        h1w[(jh0 + c) * NB + b0 + b] = og * tanhf(cn);
      }
    } else {
      if (it >= 2) {
        int idx = tid & 255;
        int o2 = idx & 1, b = (idx >> 1) & 15, ks = idx >> 5;
        float acc = 0;
        const float* hq = h1r + b0 + b;   // h1[it-2]
#pragma unroll 8
        for (int k = 32 * ks; k < 32 * ks + 32; ++k)
          acc += Wlin2[o2 * 256 + k] * hq[k * NB];
        redO[(o2 * 16 + b) * 9 + ks] = acc;
      }
    }
    __syncthreads();   // S3

    // ---- release: h0[it], h1[it-1] are published; flag early so propagation
    //      overlaps OUT-final + next poll. (h1 triple-buffer makes this safe.)
    if (it <= TSEQ && tid == 0) {
      __builtin_amdgcn_fence(__ATOMIC_RELEASE, "agent");
      __hip_atomic_store(&flags[myflag], (unsigned)(it + 1),
                         __ATOMIC_RELAXED, __HIP_MEMORY_SCOPE_AGENT);
    }

    // ================= D: OUT-final, step = it-2 =================
    if (it >= 2 && tid < 32) {
      int o2 = tid & 1, b = tid >> 1;
      float s = 0;
#pragma unroll
      for (int q = 0; q < 8; ++q) s += redO[(o2 * 16 + b) * 9 + q];
      s += blinS[o2];
      out[(size_t)(b0 + b) * (TSEQ * NOUT) + (size_t)(it - 2) * NOUT + (2 * j + o2)] = s;
    }
  }
}

extern "C" void kernel_launch(void* const* d_in, const int* in_sizes, int n_in,
                              void* d_out, int out_size, void* d_ws, size_t ws_size,
                              hipStream_t stream) {
  const float* x    = (const float*)d_in[0];
  const float* Wih0 = (const float*)d_in[1];
  const float* Whh0 = (const float*)d_in[2];
  const float* bih0 = (const float*)d_in[3];
  const float* bhh0 = (const float*)d_in[4];
  const float* Wih1 = (const float*)d_in[5];
  const float* Whh1 = (const float*)d_in[6];
  const float* bih1 = (const float*)d_in[7];
  const float* bhh1 = (const float*)d_in[8];
  const float* Wlin = (const float*)d_in[9];
  const float* blin = (const float*)d_in[10];
  float* out = (float*)d_out;

  char* ws = (char*)d_ws;
  unsigned* flags = (unsigned*)ws;                        // [0, 16KB): 8 groups x 32 x 64B
  float* h0T = (float*)(ws + 16384);                      // 2 x 32768 floats
  float* h1T = (float*)(ws + 16384 + 262144);             // 3 x 32768 floats (ends 671744)
  float* xT  = (float*)(ws + (1 << 20));                  // 32 MB

  const size_t need_xT = (size_t)(1 << 20) + (size_t)TSEQ * NIN * NB * sizeof(float);
  const int use_xT = (ws_size >= need_xT) ? 1 : 0;

  // zero flags + h state (covers [0, 1MB))
  size_t zbytes = (ws_size < (size_t)(1 << 20)) ? ws_size : (size_t)(1 << 20);
  hipMemsetAsync(d_ws, 0, zbytes, stream);

  if (use_xT) xpose_kernel<<<TSEQ, 256, 0, stream>>>(x, xT);

  lstm_persist<<<NWG, NTHR, 0, stream>>>(
      x, Wih0, Whh0, bih0, bhh0, Wih1, Whh1, bih1, bhh1, Wlin, blin,
      out, h0T, h1T, xT, flags, use_xT);
}

// Round 5
// 8015.108 us; speedup vs baseline: 2.5829x; 1.7027x over previous
//
#include <hip/hip_runtime.h>
#include <math.h>

#define TSEQ 1024
#define NB   128
#define NIN  64
#define NH   256
#define NOUT 64
#define NWG  256
#define NTHR 512
#define HS   (NH * NB)   // 32768 floats per h buffer

// -------- input transpose: x[b][t][k] -> xT[t][k][b] --------
__global__ void xpose_kernel(const float* __restrict__ in, float* __restrict__ xT) {
  __shared__ float tile[64 * 129];
  const int t = blockIdx.x;
  {
    const int b  = threadIdx.x >> 1;          // 0..127
    const int k0 = (threadIdx.x & 1) * 32;    // 0 or 32
    const float* src = in + (size_t)b * (TSEQ * NIN) + (size_t)t * NIN + k0;
#pragma unroll 8
    for (int k = 0; k < 32; ++k) tile[(k0 + k) * 129 + b] = src[k];
  }
  __syncthreads();
  {
    const int k  = threadIdx.x >> 2;          // 0..63
    const int b0 = (threadIdx.x & 3) * 32;    // 0,32,64,96
    float* dst = xT + (size_t)t * (NIN * NB) + (size_t)k * NB + b0;
#pragma unroll 8
    for (int i = 0; i < 32; ++i) dst[i] = tile[k * 129 + b0 + i];
  }
}

__device__ __forceinline__ float sigm(float v) { return 1.0f / (1.0f + expf(-v)); }

// in-row DPP reduce toward LOWER lanes: row_shl:N -> lane i reads lane i+N.
// After shl 4,2,1 with bound_ctrl, position 0 holds sum of positions 0..7 and
// position 8 holds sum of 8..15 (each 16-lane row) => writer lane kp==0.
#define DPP_ADD(a, ctrl) do {                                                   \
  int _t = __builtin_amdgcn_update_dpp(0, __float_as_int(a), ctrl, 0xf, 0xf, true); \
  (a) += __int_as_float(_t); } while (0)

// acc[4][8] += w4[g] * hv[b]  (h in two float4s)
#define FMA32(w4, v0, v1) do {                                            \
  _Pragma("unroll")                                                        \
  for (int g = 0; g < 4; ++g) {                                            \
    float wg = (g == 0) ? (w4).x : (g == 1) ? (w4).y : (g == 2) ? (w4).z : (w4).w; \
    acc[g][0] += wg * (v0).x; acc[g][1] += wg * (v0).y;                    \
    acc[g][2] += wg * (v0).z; acc[g][3] += wg * (v0).w;                    \
    acc[g][4] += wg * (v1).x; acc[g][5] += wg * (v1).y;                    \
    acc[g][6] += wg * (v1).z; acc[g][7] += wg * (v1).w;                    \
  } } while (0)

// -------- persistent 2-layer LSTM kernel --------
// wg: a = bid&7 (batch group, 16 rows), j = bid>>3 (col-tile, 8 h-cols).
// h exchanged via agent-scope (sc1) relaxed atomics only: coherent at L3,
// no L2 writeback/invalidate fences. Release = __syncthreads (vmcnt drain)
// + relaxed sc1 flag store; acquire = control dep on sc1 poll.
// Gates: lane=(cl,kp), wave=(bh,kw4); 32 accs/lane; DPP kp-reduction.
__global__ __launch_bounds__(NTHR, 1) void lstm_persist(
    const float* __restrict__ x,
    const float* __restrict__ Wih0, const float* __restrict__ Whh0,
    const float* __restrict__ bih0, const float* __restrict__ bhh0,
    const float* __restrict__ Wih1, const float* __restrict__ Whh1,
    const float* __restrict__ bih1, const float* __restrict__ bhh1,
    const float* __restrict__ Wlin, const float* __restrict__ blin,
    float* __restrict__ out,
    float* __restrict__ h0T, float* __restrict__ h1T,
    const float* __restrict__ xT, unsigned* __restrict__ flags, int use_xT)
{
  __shared__ float Wt0[320 * 32];   // [k][c*4+g], k 0..63 x-part, 64..319 h-part (40KB)
  __shared__ float Wt1[512 * 32];   // [k][c*4+g], k 0..255 h0, 256..511 h1 (64KB)
  __shared__ float Wlin2[2 * 256];
  __shared__ float red[8 * 580];    // [slice][cg*18 + b]; slices 0-3 L0/kw4, 4-7 L1/kw4
  __shared__ float redO[288];       // [(o2*16+b)*9 + ks]
  __shared__ float bias0[32], bias1[32], blinS[2];
  __shared__ float c0l[128], c1l[128];
  __shared__ float hs0[256 * 16];   // staged h0[it-1] slice [k][16b] (16KB)
  __shared__ float hs1[256 * 16];   // staged h1[it-2] slice (16KB)

  const int tid  = threadIdx.x;
  const int a    = blockIdx.x & 7;
  const int j    = blockIdx.x >> 3;
  const int b0   = a * 16;
  const int jh0  = j * 8;
  const int lane = tid & 63;
  const int wv   = tid >> 6;      // wave 0..7
  const int bh   = wv & 1;        // b-half (8 floats)
  const int kw4  = wv >> 1;       // k-quarter
  const int cl   = lane >> 3;     // col 0..7
  const int kp   = lane & 7;      // k-phase
  const int kq   = kw4 * 8 + kp;  // k offset within each 32-block

  // ---- one-time: weights into LDS ----
  for (int idx = tid; idx < 32 * 320; idx += NTHR) {
    int row = idx / 320, k = idx % 320;
    int c = row >> 2, g = row & 3;
    int grow = g * 256 + jh0 + c;
    float v = (k < 64) ? Wih0[grow * 64 + k] : Whh0[grow * 256 + (k - 64)];
    Wt0[k * 32 + row] = v;
  }
  for (int idx = tid; idx < 32 * 512; idx += NTHR) {
    int row = idx >> 9, k = idx & 511;
    int c = row >> 2, g = row & 3;
    int grow = g * 256 + jh0 + c;
    float v = (k < 256) ? Wih1[grow * 256 + k] : Whh1[grow * 256 + (k - 256)];
    Wt1[k * 32 + row] = v;
  }
  if (tid < 512) {
    int o2 = tid >> 8, k = tid & 255;
    Wlin2[tid] = Wlin[(2 * j + o2) * 256 + k];
  }
  if (tid < 32) {
    int c = tid >> 2, g = tid & 3;
    int grow = g * 256 + jh0 + c;
    bias0[tid] = bih0[grow] + bhh0[grow];
    bias1[tid] = bih1[grow] + bhh1[grow];
  }
  if (tid < 2) blinS[tid] = blin[2 * j + tid];
  if (tid < 128) { c0l[tid] = 0.0f; c1l[tid] = 0.0f; }
  __syncthreads();

  const int myflag = (a * 32 + j) * 16;

  for (int it = 0; it <= TSEQ + 1; ++it) {
    // ---- poll group flags (sc1 relaxed loads; acquire via control dep + S1) ----
    if (it >= 1 && tid < 64) {
      const unsigned tgt = (unsigned)it;
      const int fi = (a * 32 + (tid & 31)) * 16;
      while (true) {
        unsigned v = __hip_atomic_load(&flags[fi], __ATOMIC_RELAXED, __HIP_MEMORY_SCOPE_AGENT);
        if (__ballot(v >= tgt) == ~0ull) break;
        __builtin_amdgcn_s_sleep(1);
      }
    }
    __syncthreads();   // S1

    const float* h0r = h0T + ((it + 1) & 1) * HS;   // h0[it-1]
    float*       h0w = h0T + (it & 1) * HS;         // h0[it]
    const float* h1r = h1T + ((it + 1) % 3) * HS;   // h1[it-2]
    float*       h1w = h1T + ((it + 2) % 3) * HS;   // h1[it-1]

    // ---- stage hs0 <- h0[it-1], hs1 <- h1[it-2] via sc1 8B loads ----
#pragma unroll
    for (int q = 0; q < 4; ++q) {
      int f = q * 512 + tid;          // ull index 0..2047
      int k = f >> 3, bi = f & 7;
      unsigned long long v0 = __hip_atomic_load(
          (const unsigned long long*)(h0r + (size_t)k * NB + b0) + bi,
          __ATOMIC_RELAXED, __HIP_MEMORY_SCOPE_AGENT);
      unsigned long long v1 = __hip_atomic_load(
          (const unsigned long long*)(h1r + (size_t)k * NB + b0) + bi,
          __ATOMIC_RELAXED, __HIP_MEMORY_SCOPE_AGENT);
      *(unsigned long long*)&hs0[f * 2] = v0;
      *(unsigned long long*)&hs1[f * 2] = v1;
    }
    __syncthreads();   // S2

    // ================= gates: L0(it) then L1(it-1), same regs =================
    if (it < TSEQ) {
      float acc[4][8];
#pragma unroll
      for (int g = 0; g < 4; ++g)
#pragma unroll
        for (int b = 0; b < 8; ++b) acc[g][b] = 0.0f;
      if (use_xT) {
#pragma unroll
        for (int j2 = 0; j2 < 2; ++j2) {
          int k = j2 * 32 + kq;
          float4 w4 = *(const float4*)&Wt0[k * 32 + cl * 4];
          const float* xp = xT + (size_t)it * (NIN * NB) + (size_t)k * NB + b0 + bh * 8;
          float4 v0 = *(const float4*)xp;
          float4 v1 = *(const float4*)(xp + 4);
          FMA32(w4, v0, v1);
        }
      } else {
#pragma unroll
        for (int j2 = 0; j2 < 2; ++j2) {
          int k = j2 * 32 + kq;
          float4 w4 = *(const float4*)&Wt0[k * 32 + cl * 4];
          float xv[8];
#pragma unroll
          for (int b = 0; b < 8; ++b)
            xv[b] = x[(size_t)(b0 + bh * 8 + b) * (TSEQ * NIN) + (size_t)it * NIN + k];
          float4 v0 = make_float4(xv[0], xv[1], xv[2], xv[3]);
          float4 v1 = make_float4(xv[4], xv[5], xv[6], xv[7]);
          FMA32(w4, v0, v1);
        }
      }
#pragma unroll 4
      for (int j2 = 2; j2 < 10; ++j2) {
        int k = j2 * 32 + kq;
        float4 w4 = *(const float4*)&Wt0[k * 32 + cl * 4];
        const float* hp = &hs0[(k - 64) * 16 + bh * 8];
        float4 v0 = *(const float4*)hp;
        float4 v1 = *(const float4*)(hp + 4);
        FMA32(w4, v0, v1);
      }
#pragma unroll
      for (int g = 0; g < 4; ++g)
#pragma unroll
        for (int b = 0; b < 8; ++b) {
          DPP_ADD(acc[g][b], 0x104);  // row_shl:4
          DPP_ADD(acc[g][b], 0x102);  // row_shl:2
          DPP_ADD(acc[g][b], 0x101);  // row_shl:1
        }
      if (kp == 0) {
        int sbase = kw4 * 580 + (cl * 4) * 18 + bh * 8;
#pragma unroll
        for (int g = 0; g < 4; ++g)
#pragma unroll
          for (int b2 = 0; b2 < 4; ++b2)
            *(float2*)&red[sbase + g * 18 + 2 * b2] =
                make_float2(acc[g][2 * b2], acc[g][2 * b2 + 1]);
      }
    }
    if (it >= 1 && it <= TSEQ) {
      float acc[4][8];
#pragma unroll
      for (int g = 0; g < 4; ++g)
#pragma unroll
        for (int b = 0; b < 8; ++b) acc[g][b] = 0.0f;
#pragma unroll 4
      for (int j2 = 0; j2 < 8; ++j2) {
        int k = j2 * 32 + kq;
        float4 w4 = *(const float4*)&Wt1[k * 32 + cl * 4];
        const float* hp = &hs0[k * 16 + bh * 8];
        float4 v0 = *(const float4*)hp;
        float4 v1 = *(const float4*)(hp + 4);
        FMA32(w4, v0, v1);
      }
#pragma unroll 4
      for (int j2 = 8; j2 < 16; ++j2) {
        int k = j2 * 32 + kq;
        float4 w4 = *(const float4*)&Wt1[k * 32 + cl * 4];
        const float* hp = &hs1[(k - 256) * 16 + bh * 8];
        float4 v0 = *(const float4*)hp;
        float4 v1 = *(const float4*)(hp + 4);
        FMA32(w4, v0, v1);
      }
#pragma unroll
      for (int g = 0; g < 4; ++g)
#pragma unroll
        for (int b = 0; b < 8; ++b) {
          DPP_ADD(acc[g][b], 0x104);  // row_shl:4
          DPP_ADD(acc[g][b], 0x102);  // row_shl:2
          DPP_ADD(acc[g][b], 0x101);  // row_shl:1
        }
      if (kp == 0) {
        int sbase = (4 + kw4) * 580 + (cl * 4) * 18 + bh * 8;
#pragma unroll
        for (int g = 0; g < 4; ++g)
#pragma unroll
          for (int b2 = 0; b2 < 4; ++b2)
            *(float2*)&red[sbase + g * 18 + 2 * b2] =
                make_float2(acc[g][2 * b2], acc[g][2 * b2 + 1]);
      }
    }
    __syncthreads();   // S3

    // ============ acts: act0 | act1 | OUT-partial ============
    if (tid < 128) {
      if (it < TSEQ) {
        int c = tid >> 4, b = tid & 15;
        float s0 = bias0[c * 4 + 0], s1 = bias0[c * 4 + 1];
        float s2 = bias0[c * 4 + 2], s3 = bias0[c * 4 + 3];
#pragma unroll
        for (int s = 0; s < 4; ++s) {
          int base = s * 580 + (c * 4) * 18 + b;
          s0 += red[base];      s1 += red[base + 18];
          s2 += red[base + 36]; s3 += red[base + 54];
        }
        float ig = sigm(s0), fg = sigm(s1), gg = tanhf(s2), og = sigm(s3);
        float cn = fg * c0l[tid] + ig * gg;
        c0l[tid] = cn;
        __hip_atomic_store(&h0w[(jh0 + c) * NB + b0 + b], og * tanhf(cn),
                           __ATOMIC_RELAXED, __HIP_MEMORY_SCOPE_AGENT);
      }
    } else if (tid < 256) {
      if (it >= 1 && it <= TSEQ) {
        int idx = tid - 128;
        int c = idx >> 4, b = idx & 15;
        float s0 = bias1[c * 4 + 0], s1 = bias1[c * 4 + 1];
        float s2 = bias1[c * 4 + 2], s3 = bias1[c * 4 + 3];
#pragma unroll
        for (int s = 4; s < 8; ++s) {
          int base = s * 580 + (c * 4) * 18 + b;
          s0 += red[base];      s1 += red[base + 18];
          s2 += red[base + 36]; s3 += red[base + 54];
        }
        float ig = sigm(s0), fg = sigm(s1), gg = tanhf(s2), og = sigm(s3);
        float cn = fg * c1l[idx] + ig * gg;
        c1l[idx] = cn;
        __hip_atomic_store(&h1w[(jh0 + c) * NB + b0 + b], og * tanhf(cn),
                           __ATOMIC_RELAXED, __HIP_MEMORY_SCOPE_AGENT);
      }
    } else {
      if (it >= 2) {
        int idx = tid & 255;
        int o2 = idx & 1, b = (idx >> 1) & 15, ks = idx >> 5;
        float acc = 0.0f;
#pragma unroll 8
        for (int k = 32 * ks; k < 32 * ks + 32; ++k)
          acc += Wlin2[o2 * 256 + k] * hs1[k * 16 + b];
        redO[(o2 * 16 + b) * 9 + ks] = acc;
      }
    }
    __syncthreads();   // S4: drains vmcnt(0) for all sc1 stores (release point)

    if (it <= TSEQ && tid == 0) {
      asm volatile("" ::: "memory");
      __hip_atomic_store(&flags[myflag], (unsigned)(it + 1),
                         __ATOMIC_RELAXED, __HIP_MEMORY_SCOPE_AGENT);
    }

    // ---- OUT-final for t = it-2 (overlaps next poll) ----
    if (it >= 2 && tid < 32) {
      int o2 = tid & 1, b = tid >> 1;
      float s = blinS[o2];
#pragma unroll
      for (int q = 0; q < 8; ++q) s += redO[(o2 * 16 + b) * 9 + q];
      out[(size_t)(b0 + b) * (TSEQ * NOUT) + (size_t)(it - 2) * NOUT + (2 * j + o2)] = s;
    }
  }
}

extern "C" void kernel_launch(void* const* d_in, const int* in_sizes, int n_in,
                              void* d_out, int out_size, void* d_ws, size_t ws_size,
                              hipStream_t stream) {
  const float* x    = (const float*)d_in[0];
  const float* Wih0 = (const float*)d_in[1];
  const float* Whh0 = (const float*)d_in[2];
  const float* bih0 = (const float*)d_in[3];
  const float* bhh0 = (const float*)d_in[4];
  const float* Wih1 = (const float*)d_in[5];
  const float* Whh1 = (const float*)d_in[6];
  const float* bih1 = (const float*)d_in[7];
  const float* bhh1 = (const float*)d_in[8];
  const float* Wlin = (const float*)d_in[9];
  const float* blin = (const float*)d_in[10];
  float* out = (float*)d_out;

  char* ws = (char*)d_ws;
  unsigned* flags = (unsigned*)ws;                        // [0, 16KB)
  float* h0T = (float*)(ws + 16384);                      // 2 x 32768 floats
  float* h1T = (float*)(ws + 16384 + 262144);             // 3 x 32768 floats
  float* xT  = (float*)(ws + (1 << 20));                  // 32 MB

  const size_t need_xT = (size_t)(1 << 20) + (size_t)TSEQ * NIN * NB * sizeof(float);
  const int use_xT = (ws_size >= need_xT) ? 1 : 0;

  size_t zbytes = (ws_size < (size_t)(1 << 20)) ? ws_size : (size_t)(1 << 20);
  hipMemsetAsync(d_ws, 0, zbytes, stream);

  if (use_xT) xpose_kernel<<<TSEQ, 256, 0, stream>>>(x, xT);

  lstm_persist<<<NWG, NTHR, 0, stream>>>(
      x, Wih0, Whh0, bih0, bhh0, Wih1, Whh1, bih1, bhh1, Wlin, blin,
      out, h0T, h1T, xT, flags, use_xT);
}

// Round 6
// 6664.896 us; speedup vs baseline: 3.1062x; 1.2026x over previous
//
#include <hip/hip_runtime.h>
#include <math.h>

#define TSEQ 1024
#define NB   128
#define NIN  64
#define NH   256
#define NOUT 64
#define NWG  256
#define NTHR 512
#define HS   (NH * NB)   // 32768 floats per h buffer

// -------- input transpose: x[b][t][k] -> xT[t][k][b] --------
__global__ void xpose_kernel(const float* __restrict__ in, float* __restrict__ xT) {
  __shared__ float tile[64 * 129];
  const int t = blockIdx.x;
  {
    const int b  = threadIdx.x >> 1;
    const int k0 = (threadIdx.x & 1) * 32;
    const float* src = in + (size_t)b * (TSEQ * NIN) + (size_t)t * NIN + k0;
#pragma unroll 8
    for (int k = 0; k < 32; ++k) tile[(k0 + k) * 129 + b] = src[k];
  }
  __syncthreads();
  {
    const int k  = threadIdx.x >> 2;
    const int b0 = (threadIdx.x & 3) * 32;
    float* dst = xT + (size_t)t * (NIN * NB) + (size_t)k * NB + b0;
#pragma unroll 8
    for (int i = 0; i < 32; ++i) dst[i] = tile[k * 129 + b0 + i];
  }
}

__device__ __forceinline__ float sigm(float v) { return 1.0f / (1.0f + expf(-v)); }

// DPP reduce toward LOWER lanes (row_shl) — verified round 5.
#define DPP_ADD(a, ctrl) do {                                                   \
  int _t = __builtin_amdgcn_update_dpp(0, __float_as_int(a), ctrl, 0xf, 0xf, true); \
  (a) += __int_as_float(_t); } while (0)

#define FMA32(w4, v0, v1) do {                                            \
  _Pragma("unroll")                                                        \
  for (int g = 0; g < 4; ++g) {                                            \
    float wg = (g == 0) ? (w4).x : (g == 1) ? (w4).y : (g == 2) ? (w4).z : (w4).w; \
    acc[g][0] += wg * (v0).x; acc[g][1] += wg * (v0).y;                    \
    acc[g][2] += wg * (v0).z; acc[g][3] += wg * (v0).w;                    \
    acc[g][4] += wg * (v1).x; acc[g][5] += wg * (v1).y;                    \
    acc[g][6] += wg * (v1).z; acc[g][7] += wg * (v1).w;                    \
  } } while (0)

// Step structure (chain-minimized):
//  W: OUT-partial(it-3) from OLD hs1 + issue xT loads   [hides flag propagation]
//  poll -> S1 -> issue sc1 stage loads -> x-part FMA    [hides L3 latency]
//  -> LDS hs write (XOR-swizzled) -> S2 -> gates(24 it) -> S3
//  -> acts0 | acts1 | OUT-final -> S4 -> flag release
__global__ __launch_bounds__(NTHR, 1) void lstm_persist(
    const float* __restrict__ x,
    const float* __restrict__ Wih0, const float* __restrict__ Whh0,
    const float* __restrict__ bih0, const float* __restrict__ bhh0,
    const float* __restrict__ Wih1, const float* __restrict__ Whh1,
    const float* __restrict__ bih1, const float* __restrict__ bhh1,
    const float* __restrict__ Wlin, const float* __restrict__ blin,
    float* __restrict__ out,
    float* __restrict__ h0T, float* __restrict__ h1T,
    const float* __restrict__ xT, unsigned* __restrict__ flags, int use_xT)
{
  __shared__ float Wt0[320 * 32];   // [k][c*4+g] (40KB)
  __shared__ float Wt1[512 * 32];   // [k][c*4+g] (64KB)
  __shared__ float Wlin2[2 * 256];
  __shared__ float red[8 * 580];    // slices 0-3 L0/kw4, 4-7 L1/kw4
  __shared__ float redO[32 * 17];   // [(o2*16+b)*17 + ks]
  __shared__ float bias0[32], bias1[32], blinS[2];
  __shared__ float hs0[256 * 16];   // h0[it-1], XOR-swizzled rows
  __shared__ float hs1[256 * 16];   // h1[it-2], XOR-swizzled rows

  const int tid  = threadIdx.x;
  const int a    = blockIdx.x & 7;
  const int j    = blockIdx.x >> 3;
  const int b0   = a * 16;
  const int jh0  = j * 8;
  const int lane = tid & 63;
  const int wv   = tid >> 6;
  const int bh   = wv & 1;
  const int kw4  = wv >> 1;
  const int cl   = lane >> 3;
  const int kp   = lane & 7;
  const int kq   = kw4 * 8 + kp;
  const int bhx  = (bh ^ ((kp >> 1) & 1)) * 8;   // swizzled half offset for hs reads

  // OUT-partial mapping (all 512 threads): k = kk*16 + ks
  const int oo2 = tid >> 8;
  const int ob  = tid & 15;
  const int oks = (tid & 255) >> 4;
  const int obsw = ob ^ (((oks >> 1) & 1) * 8);  // swizzled b for hs1 rows k (k bit1 = ks bit1)

  // ---- one-time: weights into LDS ----
  for (int idx = tid; idx < 32 * 320; idx += NTHR) {
    int row = idx / 320, k = idx % 320;
    int c = row >> 2, g = row & 3;
    int grow = g * 256 + jh0 + c;
    float v = (k < 64) ? Wih0[grow * 64 + k] : Whh0[grow * 256 + (k - 64)];
    Wt0[k * 32 + row] = v;
  }
  for (int idx = tid; idx < 32 * 512; idx += NTHR) {
    int row = idx >> 9, k = idx & 511;
    int c = row >> 2, g = row & 3;
    int grow = g * 256 + jh0 + c;
    float v = (k < 256) ? Wih1[grow * 256 + k] : Whh1[grow * 256 + (k - 256)];
    Wt1[k * 32 + row] = v;
  }
  if (tid < 512) {
    int o2 = tid >> 8, k = tid & 255;
    Wlin2[tid] = Wlin[(2 * j + o2) * 256 + k];
  }
  if (tid < 32) {
    int c = tid >> 2, g = tid & 3;
    int grow = g * 256 + jh0 + c;
    bias0[tid] = bih0[grow] + bhh0[grow];
    bias1[tid] = bih1[grow] + bhh1[grow];
  }
  if (tid < 2) blinS[tid] = blin[2 * j + tid];
  __syncthreads();

  const int myflag = (a * 32 + j) * 16;
  float cstate = 0.0f;   // c0 for tid<128, c1 for tid in [128,256)

  for (int it = 0; it <= TSEQ + 2; ++it) {
    const float* h0r = h0T + ((it + 1) & 1) * HS;   // h0[it-1]
    float*       h0w = h0T + (it & 1) * HS;         // h0[it]
    const float* h1r = h1T + ((it + 1) % 3) * HS;   // h1[it-2]
    float*       h1w = h1T + ((it + 2) % 3) * HS;   // h1[it-1]

    // ======== W: xT prefetch + OUT-partial(it-3) on OLD hs1 ========
    float4 xv[2][2];
    if (it < TSEQ) {
      if (use_xT) {
#pragma unroll
        for (int j2 = 0; j2 < 2; ++j2) {
          int k = j2 * 32 + kq;
          const float* xp = xT + (size_t)it * (NIN * NB) + (size_t)k * NB + b0 + bh * 8;
          xv[j2][0] = *(const float4*)xp;
          xv[j2][1] = *(const float4*)(xp + 4);
        }
      } else {
#pragma unroll
        for (int j2 = 0; j2 < 2; ++j2) {
          int k = j2 * 32 + kq;
          const float* xb = x + (size_t)(b0 + bh * 8) * (TSEQ * NIN) + (size_t)it * NIN + k;
          float xs[8];
#pragma unroll
          for (int b = 0; b < 8; ++b) xs[b] = xb[(size_t)b * (TSEQ * NIN)];
          xv[j2][0] = make_float4(xs[0], xs[1], xs[2], xs[3]);
          xv[j2][1] = make_float4(xs[4], xs[5], xs[6], xs[7]);
        }
      }
    }
    if (it >= 3) {
      float acc = 0.0f;
#pragma unroll 4
      for (int kk = 0; kk < 16; ++kk) {
        int k = kk * 16 + oks;
        acc += Wlin2[oo2 * 256 + k] * hs1[k * 16 + obsw];
      }
      redO[(oo2 * 16 + ob) * 17 + oks] = acc;
    }

    // ======== poll group flags ========
    if (it >= 1 && it <= TSEQ + 1 && tid < 64) {
      const unsigned tgt = (unsigned)it;
      const int fi = (a * 32 + (tid & 31)) * 16;
      while (true) {
        unsigned v = __hip_atomic_load(&flags[fi], __ATOMIC_RELAXED, __HIP_MEMORY_SCOPE_AGENT);
        if (__ballot(v >= tgt) == ~0ull) break;
        __builtin_amdgcn_s_sleep(1);
      }
    }
    __syncthreads();   // S1 (also orders OUT-partial reads before hs overwrite)

    // ======== stage issue (sc1) -> x-part FMA (latency hiding) -> LDS write ========
    unsigned long long s0[4], s1[4];
    const int stage_on = (it <= TSEQ + 1);
    if (stage_on) {
#pragma unroll
      for (int q = 0; q < 4; ++q) {
        int f = q * 512 + tid;
        int k = f >> 3, bi = f & 7;
        s0[q] = __hip_atomic_load(
            (const unsigned long long*)(h0r + (size_t)k * NB + b0) + bi,
            __ATOMIC_RELAXED, __HIP_MEMORY_SCOPE_AGENT);
        s1[q] = __hip_atomic_load(
            (const unsigned long long*)(h1r + (size_t)k * NB + b0) + bi,
            __ATOMIC_RELAXED, __HIP_MEMORY_SCOPE_AGENT);
      }
    }

    float accL0[4][8];
#pragma unroll
    for (int g = 0; g < 4; ++g)
#pragma unroll
      for (int b = 0; b < 8; ++b) accL0[g][b] = 0.0f;
    if (it < TSEQ) {
      float (*acc)[8] = accL0;
#pragma unroll
      for (int j2 = 0; j2 < 2; ++j2) {
        float4 w4 = *(const float4*)&Wt0[(j2 * 32 + kq) * 32 + cl * 4];
        FMA32(w4, xv[j2][0], xv[j2][1]);
      }
    }

    if (stage_on) {
#pragma unroll
      for (int q = 0; q < 4; ++q) {
        int f = q * 512 + tid;
        int k = f >> 3, bi = f & 7;
        int off = k * 16 + ((bi * 2) ^ (((k >> 1) & 1) * 8));
        *(unsigned long long*)&hs0[off] = s0[q];
        *(unsigned long long*)&hs1[off] = s1[q];
      }
    }
    __syncthreads();   // S2

    // ======== gates: L0 h-part (8) + L1 (16) ========
    if (it < TSEQ) {
      float (*acc)[8] = accL0;
#pragma unroll 4
      for (int j2 = 0; j2 < 8; ++j2) {
        int kr = j2 * 32 + kq;
        float4 w4 = *(const float4*)&Wt0[(64 + kr) * 32 + cl * 4];
        const float* hp = &hs0[kr * 16 + bhx];
        float4 v0 = *(const float4*)hp;
        float4 v1 = *(const float4*)(hp + 4);
        FMA32(w4, v0, v1);
      }
#pragma unroll
      for (int g = 0; g < 4; ++g)
#pragma unroll
        for (int b = 0; b < 8; ++b) {
          DPP_ADD(acc[g][b], 0x104);
          DPP_ADD(acc[g][b], 0x102);
          DPP_ADD(acc[g][b], 0x101);
        }
      if (kp == 0) {
        int sbase = kw4 * 580 + (cl * 4) * 18 + bh * 8;
#pragma unroll
        for (int g = 0; g < 4; ++g)
#pragma unroll
          for (int b2 = 0; b2 < 4; ++b2)
            *(float2*)&red[sbase + g * 18 + 2 * b2] =
                make_float2(acc[g][2 * b2], acc[g][2 * b2 + 1]);
      }
    }
    if (it >= 1 && it <= TSEQ) {
      float acc[4][8];
#pragma unroll
      for (int g = 0; g < 4; ++g)
#pragma unroll
        for (int b = 0; b < 8; ++b) acc[g][b] = 0.0f;
#pragma unroll 4
      for (int j2 = 0; j2 < 8; ++j2) {
        int kr = j2 * 32 + kq;
        float4 w4 = *(const float4*)&Wt1[kr * 32 + cl * 4];
        const float* hp = &hs0[kr * 16 + bhx];
        float4 v0 = *(const float4*)hp;
        float4 v1 = *(const float4*)(hp + 4);
        FMA32(w4, v0, v1);
      }
#pragma unroll 4
      for (int j2 = 0; j2 < 8; ++j2) {
        int kr = j2 * 32 + kq;
        float4 w4 = *(const float4*)&Wt1[(256 + kr) * 32 + cl * 4];
        const float* hp = &hs1[kr * 16 + bhx];
        float4 v0 = *(const float4*)hp;
        float4 v1 = *(const float4*)(hp + 4);
        FMA32(w4, v0, v1);
      }
#pragma unroll
      for (int g = 0; g < 4; ++g)
#pragma unroll
        for (int b = 0; b < 8; ++b) {
          DPP_ADD(acc[g][b], 0x104);
          DPP_ADD(acc[g][b], 0x102);
          DPP_ADD(acc[g][b], 0x101);
        }
      if (kp == 0) {
        int sbase = (4 + kw4) * 580 + (cl * 4) * 18 + bh * 8;
#pragma unroll
        for (int g = 0; g < 4; ++g)
#pragma unroll
          for (int b2 = 0; b2 < 4; ++b2)
            *(float2*)&red[sbase + g * 18 + 2 * b2] =
                make_float2(acc[g][2 * b2], acc[g][2 * b2 + 1]);
      }
    }
    __syncthreads();   // S3

    // ======== acts0 | acts1 | OUT-final ========
    if (tid < 128) {
      if (it < TSEQ) {
        int c = tid >> 4, b = tid & 15;
        float s0 = bias0[c * 4 + 0], s1 = bias0[c * 4 + 1];
        float s2 = bias0[c * 4 + 2], s3 = bias0[c * 4 + 3];
#pragma unroll
        for (int s = 0; s < 4; ++s) {
          int base = s * 580 + (c * 4) * 18 + b;
          s0 += red[base];      s1 += red[base + 18];
          s2 += red[base + 36]; s3 += red[base + 54];
        }
        float ig = sigm(s0), fg = sigm(s1), gg = tanhf(s2), og = sigm(s3);
        float cn = fg * cstate + ig * gg;
        cstate = cn;
        __hip_atomic_store(&h0w[(jh0 + c) * NB + b0 + b], og * tanhf(cn),
                           __ATOMIC_RELAXED, __HIP_MEMORY_SCOPE_AGENT);
      }
    } else if (tid < 256) {
      if (it >= 1 && it <= TSEQ) {
        int idx = tid - 128;
        int c = idx >> 4, b = idx & 15;
        float s0 = bias1[c * 4 + 0], s1 = bias1[c * 4 + 1];
        float s2 = bias1[c * 4 + 2], s3 = bias1[c * 4 + 3];
#pragma unroll
        for (int s = 4; s < 8; ++s) {
          int base = s * 580 + (c * 4) * 18 + b;
          s0 += red[base];      s1 += red[base + 18];
          s2 += red[base + 36]; s3 += red[base + 54];
        }
        float ig = sigm(s0), fg = sigm(s1), gg = tanhf(s2), og = sigm(s3);
        float cn = fg * cstate + ig * gg;
        cstate = cn;
        __hip_atomic_store(&h1w[(jh0 + c) * NB + b0 + b], og * tanhf(cn),
                           __ATOMIC_RELAXED, __HIP_MEMORY_SCOPE_AGENT);
      }
    } else if (tid < 288) {
      if (it >= 3) {
        int o2 = tid & 1, b = (tid >> 1) & 15;
        float s = blinS[o2];
#pragma unroll
        for (int q = 0; q < 16; ++q) s += redO[(o2 * 16 + b) * 17 + q];
        out[(size_t)(b0 + b) * (TSEQ * NOUT) + (size_t)(it - 3) * NOUT + (2 * j + o2)] = s;
      }
    }
    __syncthreads();   // S4: drains all sc1 h-stores (release point)

    if (it <= TSEQ + 1 && tid == 0) {
      asm volatile("" ::: "memory");
      __hip_atomic_store(&flags[myflag], (unsigned)(it + 1),
                         __ATOMIC_RELAXED, __HIP_MEMORY_SCOPE_AGENT);
    }
  }
}

extern "C" void kernel_launch(void* const* d_in, const int* in_sizes, int n_in,
                              void* d_out, int out_size, void* d_ws, size_t ws_size,
                              hipStream_t stream) {
  const float* x    = (const float*)d_in[0];
  const float* Wih0 = (const float*)d_in[1];
  const float* Whh0 = (const float*)d_in[2];
  const float* bih0 = (const float*)d_in[3];
  const float* bhh0 = (const float*)d_in[4];
  const float* Wih1 = (const float*)d_in[5];
  const float* Whh1 = (const float*)d_in[6];
  const float* bih1 = (const float*)d_in[7];
  const float* bhh1 = (const float*)d_in[8];
  const float* Wlin = (const float*)d_in[9];
  const float* blin = (const float*)d_in[10];
  float* out = (float*)d_out;

  char* ws = (char*)d_ws;
  unsigned* flags = (unsigned*)ws;                        // [0, 16KB)
  float* h0T = (float*)(ws + 16384);                      // 2 x 32768 floats
  float* h1T = (float*)(ws + 16384 + 262144);             // 3 x 32768 floats
  float* xT  = (float*)(ws + (1 << 20));                  // 32 MB

  const size_t need_xT = (size_t)(1 << 20) + (size_t)TSEQ * NIN * NB * sizeof(float);
  const int use_xT = (ws_size >= need_xT) ? 1 : 0;

  size_t zbytes = (ws_size < (size_t)(1 << 20)) ? ws_size : (size_t)(1 << 20);
  hipMemsetAsync(d_ws, 0, zbytes, stream);

  if (use_xT) xpose_kernel<<<TSEQ, 256, 0, stream>>>(x, xT);

  lstm_persist<<<NWG, NTHR, 0, stream>>>(
      x, Wih0, Whh0, bih0, bhh0, Wih1, Whh1, bih1, bhh1, Wlin, blin,
      out, h0T, h1T, xT, flags, use_xT);
}